// Round 5
// baseline (278.424 us; speedup 1.0000x reference)
//
#include <hip/hip_runtime.h>

// ---------------------------------------------------------------------------
// GraphSAGE 2-layer, mean aggregation.
//   L1: h = relu( mean_nbr(x) @ W_l1 + x @ W_r1 + b1 )   (IN=2 -> aggregate x first)
//   L2: out = mean_nbr(h) @ W_l2 + h @ W_r2 + b2
// R2: CSR via 2-level MSD binning (bucket = dst>>7).
// R4: layer-2 aggregation gathers h in fp8 e4m3.
// R6: agg2: 8 nodes/wave, 8 lanes/node, 16 cols/lane; x-agg folded into
//     k_bucket_csr (LDS float atomics).
// R7: FAILED (global counting sort): 1-block scan 233us; device-scope random
//     atomics ~200us. Reverted.
// R8: NEUTRAL (XCD-seg ebuf). Reverted.
// R9/R10: bscatter pass-1 eliminated via per-(block,bucket) bases; parallel
//     k_colscan (1 wg/bucket). 246.3us, bscatter out of top-5.
// R11: k_agg2 + k_gemm FUSED (k_aggemm): one block = 32 nodes = 4 waves x
//     8 nodes (agg phase) = 2 MFMA row-tiles x 2 col-halves (gemm phase).
//     a16 (25.6MB write + 25.6MB read) replaced by 8.7KB LDS; B-frags read
//     directly from wt (64KB, L2-hot) instead of per-block LDS staging.
// ---------------------------------------------------------------------------

using f32x4 = __attribute__((ext_vector_type(4))) float;
using f32x2 = __attribute__((ext_vector_type(2))) float;
using s16x8 = __attribute__((ext_vector_type(8))) short;

__device__ __forceinline__ unsigned short f32_to_bf16(float f) {
  unsigned int u = __float_as_uint(f);
  u += 0x7fffu + ((u >> 16) & 1u);          // round-to-nearest-even
  return (unsigned short)(u >> 16);
}

#define EDGE_TILE 4096

// ---- bin pass 1: bucket histogram; stores per-block row + bucket totals -----
__global__ __launch_bounds__(256) void k_bhist(const int* __restrict__ ei, int* __restrict__ bcnt,
                                               unsigned short* __restrict__ hcnt, int E, int nb) {
  __shared__ int h[1024];
  int t = threadIdx.x;
  for (int i = t; i < nb; i += 256) h[i] = 0;
  __syncthreads();
  int tbeg = blockIdx.x * EDGE_TILE;
  int tend = min(tbeg + EDGE_TILE, E);
  const int* dstp = ei + E;
  for (int i = tbeg + t; i < tend; i += 256) atomicAdd(&h[dstp[i] >> 7], 1);
  __syncthreads();
  unsigned short* hr = hcnt + (size_t)blockIdx.x * nb;
  for (int i = t; i < nb; i += 256) {
    int c = h[i];
    hr[i] = (unsigned short)c;              // c <= EDGE_TILE=4096, fits u16
    if (c) atomicAdd(&bcnt[i], c);
  }
}

// ---- bin pass 2a: scan bucket totals -> bucket bases ------------------------
__global__ __launch_bounds__(1024) void k_bscan(const int* __restrict__ bcnt, int* __restrict__ bbase,
                                                int nb, int E) {
  __shared__ int sm[2][1024];
  int t = threadIdx.x;
  int v0 = (t < nb) ? bcnt[t] : 0;
  sm[0][t] = v0;
  __syncthreads();
  int src = 0;
  for (int st = 1; st < 1024; st <<= 1) {
    int v = sm[src][t];
    if (t >= st) v += sm[src][t - st];
    sm[src ^ 1][t] = v; __syncthreads(); src ^= 1;
  }
  if (t < nb) bbase[t] = sm[src][t] - v0;   // exclusive prefix
  if (t == 0) bbase[nb] = E;
}

// ---- bin pass 2b: per-(block,bucket) prefix along block axis (PARALLEL) -----
__global__ __launch_bounds__(256) void k_colscan(const unsigned short* __restrict__ hcnt,
                                                 unsigned short* __restrict__ rel,
                                                 int nblk, int nb) {
  __shared__ int sm[2][256];
  int b = blockIdx.x;
  int t = threadIdx.x;
  int e0 = 2 * t, e1 = 2 * t + 1;
  int a = (e0 < nblk) ? (int)hcnt[(size_t)e0 * nb + b] : 0;
  int c = (e1 < nblk) ? (int)hcnt[(size_t)e1 * nb + b] : 0;
  int s = a + c;
  sm[0][t] = s;
  __syncthreads();
  int src = 0;
  for (int st = 1; st < 256; st <<= 1) {
    int v = sm[src][t];
    if (t >= st) v += sm[src][t - st];
    sm[src ^ 1][t] = v; __syncthreads(); src ^= 1;
  }
  int excl = sm[src][t] - s;                // exclusive prefix of pair-sums
  if (e0 < nblk) rel[(size_t)e0 * nb + b] = (unsigned short)excl;
  if (e1 < nblk) rel[(size_t)e1 * nb + b] = (unsigned short)(excl + a);
}

// ---- bin pass 3: scatter packed (src<<7 | dst&127) at precomputed bases -----
__global__ __launch_bounds__(256) void k_bscatter(const int* __restrict__ ei,
                                                  const int* __restrict__ bbase,
                                                  const unsigned short* __restrict__ rel,
                                                  unsigned int* __restrict__ ebuf, int E, int nb) {
  __shared__ int h[1024];                    // in-block rank cursors
  __shared__ int base[1024];
  int t = threadIdx.x;
  const unsigned short* rr = rel + (size_t)blockIdx.x * nb;
  for (int i = t; i < nb; i += 256) {
    h[i] = 0;
    base[i] = bbase[i] + (int)rr[i];
  }
  __syncthreads();
  int tbeg = blockIdx.x * EDGE_TILE;
  int tend = min(tbeg + EDGE_TILE, E);
  const int* srcp = ei;
  const int* dstp = ei + E;
  for (int i = tbeg + t; i < tend; i += 256) {
    int d = dstp[i];
    int b = d >> 7;
    int r = atomicAdd(&h[b], 1);
    ebuf[base[b] + r] = ((unsigned)srcp[i] << 7) | (unsigned)(d & 127);
  }
}

// ---- bin pass 4: per-bucket CSR build + layer-1 x aggregation ---------------
__global__ __launch_bounds__(256) void k_bucket_csr(const unsigned int* __restrict__ ebuf,
                                                    const int* __restrict__ bbase,
                                                    const float* __restrict__ x,
                                                    int* __restrict__ offs, int* __restrict__ csr,
                                                    float* __restrict__ agg1,
                                                    int N, int nb) {
  __shared__ int deg[128];
  __shared__ int loff[128];
  __shared__ int cur[128];
  __shared__ float sx0[128];
  __shared__ float sx1[128];
  int b = blockIdx.x;
  int t = threadIdx.x;
  int lo = bbase[b], hi = bbase[b + 1];
  if (t < 128) { deg[t] = 0; sx0[t] = 0.f; sx1[t] = 0.f; }
  __syncthreads();
  const float2* x2 = (const float2*)x;
  for (int i = lo + t; i < hi; i += 256) {
    unsigned int e = ebuf[i];
    int d = e & 127;
    float2 v = x2[e >> 7];
    atomicAdd(&deg[d], 1);
    atomicAdd(&sx0[d], v.x);
    atomicAdd(&sx1[d], v.y);
  }
  __syncthreads();
  if (t < 128) loff[t] = deg[t];
  __syncthreads();
  for (int st = 1; st < 128; st <<= 1) {
    int v = 0;
    if (t < 128 && t >= st) v = loff[t - st];
    __syncthreads();
    if (t < 128) loff[t] += v;
    __syncthreads();
  }
  if (t < 128) {
    int ex = loff[t] - deg[t];                 // exclusive prefix
    cur[t] = ex;
    int node = b * 128 + t;
    if (node < N) {
      offs[node] = lo + ex;
      agg1[2 * node]     = sx0[t];
      agg1[2 * node + 1] = sx1[t];
    }
  }
  if (b == nb - 1 && t == 0) offs[N] = hi;
  __syncthreads();
  for (int i = lo + t; i < hi; i += 256) {
    unsigned int e = ebuf[i];
    int r = atomicAdd(&cur[e & 127], 1);
    csr[lo + r] = (int)(e >> 7);
  }
}

// ---- layer-1 dense: h = relu(...), bf16 + fp8 out; 2 cols/thread ------------
__global__ __launch_bounds__(256) void k_layer1(const float* __restrict__ x, const float* __restrict__ agg1,
                                                const int* __restrict__ offs,
                                                const float* __restrict__ Wl, const float* __restrict__ Wr,
                                                const float* __restrict__ b1,
                                                unsigned int* __restrict__ h16,
                                                unsigned short* __restrict__ h8, int n) {
  int gid = blockIdx.x * 256 + threadIdx.x;
  int node = gid >> 6;
  if (node >= n) return;
  int c = (gid & 63) * 2;
  int deg = offs[node + 1] - offs[node];
  float sc = 1.0f / (float)max(deg, 1);
  float a0 = agg1[2 * node] * sc, a1 = agg1[2 * node + 1] * sc;
  float x0 = x[2 * node], x1 = x[2 * node + 1];
  float r0 = fmaf(a0, Wl[c],     fmaf(a1, Wl[128 + c],     fmaf(x0, Wr[c],     fmaf(x1, Wr[128 + c],     b1[c]))));
  float r1 = fmaf(a0, Wl[c + 1], fmaf(a1, Wl[128 + c + 1], fmaf(x0, Wr[c + 1], fmaf(x1, Wr[128 + c + 1], b1[c + 1]))));
  r0 = r0 > 0.f ? r0 : 0.f;
  r1 = r1 > 0.f ? r1 : 0.f;
  unsigned int packed = (unsigned int)f32_to_bf16(r0) | ((unsigned int)f32_to_bf16(r1) << 16);
  h16[(size_t)node * 64 + (gid & 63)] = packed;
  unsigned int p8 = (unsigned int)__builtin_amdgcn_cvt_pk_fp8_f32(r0, r1, 0, false);
  h8[(size_t)node * 64 + (gid & 63)] = (unsigned short)(p8 & 0xffffu);
}

// ---- prep: Wt[col][k] bf16, k<128 from W_l2, k>=128 from W_r2 ---------------
__global__ __launch_bounds__(256) void k_prepw(const float* __restrict__ Wl2, const float* __restrict__ Wr2,
                                               unsigned short* __restrict__ wt) {
  int tid = blockIdx.x * 256 + threadIdx.x;   // tid = c*256 + k
  if (tid >= 128 * 256) return;
  int c = tid >> 8, k = tid & 255;
  float v = (k < 128) ? Wl2[k * 128 + c] : Wr2[(k - 128) * 128 + c];
  wt[tid] = f32_to_bf16(v);
}

// ---- FUSED layer-2: aggregate (fp8 gather) -> LDS -> MFMA GEMM + bias -------
// Block = 32 nodes. Phase 1: 4 waves x 8 nodes x 8 lanes x 16 cols (proven
// R6 structure), acc -> bf16 -> lds_a[32][136] (stride 136 breaks bank align).
// Phase 2: wave wv does rows (wv>>1)*16..+15, cols (wv&1)*64..+63.
// A k<128 from lds_a, A k>=128 from h16 (global), B from wt (global, L2-hot).
#define ACC8(v)                                                                              \
  do {                                                                                       \
    f32x2 p;                                                                                 \
    p = __builtin_amdgcn_cvt_pk_f32_fp8((int)(v).x, false); acc[0] += p[0];  acc[1] += p[1]; \
    p = __builtin_amdgcn_cvt_pk_f32_fp8((int)(v).x, true);  acc[2] += p[0];  acc[3] += p[1]; \
    p = __builtin_amdgcn_cvt_pk_f32_fp8((int)(v).y, false); acc[4] += p[0];  acc[5] += p[1]; \
    p = __builtin_amdgcn_cvt_pk_f32_fp8((int)(v).y, true);  acc[6] += p[0];  acc[7] += p[1]; \
    p = __builtin_amdgcn_cvt_pk_f32_fp8((int)(v).z, false); acc[8] += p[0];  acc[9] += p[1]; \
    p = __builtin_amdgcn_cvt_pk_f32_fp8((int)(v).z, true);  acc[10] += p[0]; acc[11] += p[1];\
    p = __builtin_amdgcn_cvt_pk_f32_fp8((int)(v).w, false); acc[12] += p[0]; acc[13] += p[1];\
    p = __builtin_amdgcn_cvt_pk_f32_fp8((int)(v).w, true);  acc[14] += p[0]; acc[15] += p[1];\
  } while (0)

__global__ __launch_bounds__(256) void k_aggemm(const int* __restrict__ offs, const int* __restrict__ csr,
                                                const unsigned char* __restrict__ h8,
                                                const unsigned short* __restrict__ h16,
                                                const unsigned short* __restrict__ wt,
                                                const float* __restrict__ b2,
                                                float* __restrict__ out, int n) {
  __shared__ unsigned short lds_a[32 * 136];   // 8704 B
  int wv   = threadIdx.x >> 6;
  int lane = threadIdx.x & 63;

  // ---------------- phase 1: aggregation (R6 structure) ----------------
  {
    int sub  = lane >> 3;          // node slot within wave: 0..7
    int cb   = lane & 7;           // 16-col block
    int nr   = wv * 8 + sub;       // block-local row 0..31
    int node = blockIdx.x * 32 + nr;

    float acc[16];
#pragma unroll
    for (int j = 0; j < 16; ++j) acc[j] = 0.f;
    int deg = 1;

    if (node < n) {
      int beg = offs[node];
      int end = offs[node + 1];
      deg = end - beg;
      const unsigned char* hb = h8 + cb * 16;
      int t = 0;
      for (; t + 1 < deg; t += 2) {
        int s0 = csr[beg + t];
        int s1 = csr[beg + t + 1];
        uint4 v0 = *(const uint4*)(hb + (size_t)s0 * 128);
        uint4 v1 = *(const uint4*)(hb + (size_t)s1 * 128);
        ACC8(v0);
        ACC8(v1);
      }
      if (t < deg) {
        int s0 = csr[beg + t];
        uint4 v0 = *(const uint4*)(hb + (size_t)s0 * 128);
        ACC8(v0);
      }
    }

    float scale = 1.0f / (float)max(deg, 1);
    unsigned int u[8];
#pragma unroll
    for (int k = 0; k < 8; ++k)
      u[k] = (unsigned int)f32_to_bf16(acc[2 * k] * scale) |
             ((unsigned int)f32_to_bf16(acc[2 * k + 1] * scale) << 16);
    unsigned short* dstl = lds_a + nr * 136 + cb * 16;
    *(uint4*)dstl       = make_uint4(u[0], u[1], u[2], u[3]);
    *(uint4*)(dstl + 8) = make_uint4(u[4], u[5], u[6], u[7]);
  }
  __syncthreads();

  // ---------------- phase 2: MFMA GEMM on [lds_a | h16] @ wt ----------------
  {
    int rowbase = (wv >> 1) * 16;            // 0 or 16 (block-local)
    int colbase = (wv & 1) * 64;             // 0 or 64
    int m16 = lane & 15, quad = lane >> 4;

    int r  = blockIdx.x * 32 + rowbase + m16;
    int rc = r < n ? r : n - 1;
    const unsigned short* hrow = h16 + (size_t)rc * 128 + quad * 8;
    const unsigned short* alds = lds_a + (rowbase + m16) * 136 + quad * 8;

    s16x8 afrag[8];
#pragma unroll
    for (int c4 = 0; c4 < 4; ++c4) {
      afrag[c4]     = *(const s16x8*)(alds + c4 * 32);   // k = c4*32+quad*8, from agg
      afrag[4 + c4] = *(const s16x8*)(hrow + c4 * 32);   // k-128 from h16
    }

    f32x4 acc[4];
#pragma unroll
    for (int t = 0; t < 4; ++t) acc[t] = (f32x4){0.f, 0.f, 0.f, 0.f};

    const unsigned short* bbase = wt + (size_t)(colbase + m16) * 256 + quad * 8;
#pragma unroll
    for (int ch = 0; ch < 8; ++ch) {
#pragma unroll
      for (int t = 0; t < 4; ++t) {
        // B[k][n]: n = colbase + t*16 + m16, k = ch*32 + quad*8 .. +8
        s16x8 bf = *(const s16x8*)(bbase + (size_t)t * 16 * 256 + ch * 32);
        acc[t] = __builtin_amdgcn_mfma_f32_16x16x32_bf16(afrag[ch], bf, acc[t], 0, 0, 0);
      }
    }

#pragma unroll
    for (int t = 0; t < 4; ++t) {
      int col = colbase + t * 16 + m16;
      float bias = b2[col];
#pragma unroll
      for (int i = 0; i < 4; ++i) {
        int row = blockIdx.x * 32 + rowbase + quad * 4 + i;  // col=lane&15, row=quad*4+reg
        if (row < n) out[(size_t)row * 128 + col] = acc[t][i] + bias;
      }
    }
  }
}

// ---------------------------------------------------------------------------
extern "C" void kernel_launch(void* const* d_in, const int* in_sizes, int n_in,
                              void* d_out, int out_size, void* d_ws, size_t ws_size,
                              hipStream_t stream) {
  const float* x    = (const float*)d_in[0];
  const int*   ei   = (const int*)d_in[1];
  const float* Wl1  = (const float*)d_in[2];
  const float* Wr1  = (const float*)d_in[3];
  const float* b1   = (const float*)d_in[4];
  const float* Wl2  = (const float*)d_in[5];
  const float* Wr2  = (const float*)d_in[6];
  const float* b2   = (const float*)d_in[7];
  float* out = (float*)d_out;

  const int N = in_sizes[0] / 2;     // 100000
  const int E = in_sizes[1] / 2;     // 1600000
  const int nb = (N + 127) >> 7;     // 782 buckets
  const int nblk_e = (E + EDGE_TILE - 1) / EDGE_TILE;   // 391

  // workspace carve-up (256B aligned)
  char* p = (char*)d_ws;
  auto take = [&](size_t bytes) { char* r = p; p += (bytes + 255) & ~(size_t)255; return r; };
  int* bcnt            = (int*)take(1024 * 4);
  int* bbase           = (int*)take(1025 * 4);
  unsigned short* hcnt = (unsigned short*)take((size_t)nblk_e * nb * 2);
  unsigned short* rel  = (unsigned short*)take((size_t)nblk_e * nb * 2);
  int* offs            = (int*)take((size_t)(N + 1) * 4);
  int* csr             = (int*)take((size_t)E * 4);
  unsigned int* ebuf   = (unsigned int*)take((size_t)E * 4);
  float* agg1          = (float*)take((size_t)N * 2 * 4);
  unsigned short* h16  = (unsigned short*)take((size_t)N * 128 * 2);
  unsigned short* h8   = (unsigned short*)take((size_t)N * 128);
  unsigned short* wt   = (unsigned short*)take((size_t)128 * 256 * 2);

  hipMemsetAsync(bcnt, 0, 1024 * 4, stream);

  k_bhist     <<<nblk_e, 256, 0, stream>>>(ei, bcnt, hcnt, E, nb);
  k_bscan     <<<1, 1024, 0, stream>>>(bcnt, bbase, nb, E);
  k_colscan   <<<nb, 256, 0, stream>>>(hcnt, rel, nblk_e, nb);
  k_bscatter  <<<nblk_e, 256, 0, stream>>>(ei, bbase, rel, ebuf, E, nb);
  k_bucket_csr<<<nb, 256, 0, stream>>>(ebuf, bbase, x, offs, csr, agg1, N, nb);
  k_layer1    <<<((size_t)N * 64 + 255) / 256, 256, 0, stream>>>(x, agg1, offs, Wl1, Wr1, b1,
                                                                 (unsigned int*)h16, h8, N);
  k_prepw     <<<(128 * 256) / 256, 256, 0, stream>>>(Wl2, Wr2, wt);
  k_aggemm    <<<(N + 31) / 32, 256, 0, stream>>>(offs, csr, (const unsigned char*)h8,
                                                  h16, wt, b2, out, N);
}

// Round 6
// 242.023 us; speedup vs baseline: 1.1504x; 1.1504x over previous
//
#include <hip/hip_runtime.h>

// ---------------------------------------------------------------------------
// GraphSAGE 2-layer, mean aggregation.
//   L1: h = relu( mean_nbr(x) @ W_l1 + x @ W_r1 + b1 )   (IN=2 -> aggregate x first)
//   L2: out = mean_nbr(h) @ W_l2 + h @ W_r2 + b2
// R2: CSR via 2-level MSD binning (bucket = dst>>7).
// R4: layer-2 aggregation gathers h in fp8 e4m3.
// R6: agg2: 8 nodes/wave, 8 lanes/node, 16 cols/lane.
// R7: FAILED global counting sort (1-block scan 233us; random device atomics).
// R8: NEUTRAL XCD-seg ebuf. Reverted.
// R9/R10: bscatter pass-1 eliminated (per-(block,bucket) bases + parallel
//     colscan). 246.3us.
// R11: FAILED agg2+gemm fusion (100.5us, all pipes idle): barrier couples
//     waves to per-block degree straggler. Reverted to split.
// R12: dispatch count 10 -> 7: (a) k_scans = colscan | bscan(256t) | prepw
//     by blockIdx role (all depend only on bhist/inputs); (b) layer1 folded
//     into k_bucket_csr (sx/deg already in LDS; agg1 roundtrip deleted);
//     (c) k_agg2 cross-iteration prefetch (2 rows in flight during ACC8).
// ---------------------------------------------------------------------------

using f32x4 = __attribute__((ext_vector_type(4))) float;
using f32x2 = __attribute__((ext_vector_type(2))) float;
using s16x8 = __attribute__((ext_vector_type(8))) short;

__device__ __forceinline__ unsigned short f32_to_bf16(float f) {
  unsigned int u = __float_as_uint(f);
  u += 0x7fffu + ((u >> 16) & 1u);          // round-to-nearest-even
  return (unsigned short)(u >> 16);
}

#define EDGE_TILE 4096

// ---- bin pass 1: bucket histogram; stores per-block row + bucket totals -----
__global__ __launch_bounds__(256) void k_bhist(const int* __restrict__ ei, int* __restrict__ bcnt,
                                               unsigned short* __restrict__ hcnt, int E, int nb) {
  __shared__ int h[1024];
  int t = threadIdx.x;
  for (int i = t; i < nb; i += 256) h[i] = 0;
  __syncthreads();
  int tbeg = blockIdx.x * EDGE_TILE;
  int tend = min(tbeg + EDGE_TILE, E);
  const int* dstp = ei + E;
  for (int i = tbeg + t; i < tend; i += 256) atomicAdd(&h[dstp[i] >> 7], 1);
  __syncthreads();
  unsigned short* hr = hcnt + (size_t)blockIdx.x * nb;
  for (int i = t; i < nb; i += 256) {
    int c = h[i];
    hr[i] = (unsigned short)c;              // c <= EDGE_TILE=4096, fits u16
    if (c) atomicAdd(&bcnt[i], c);
  }
}

// ---- pass 2 (ONE launch, role by blockIdx):
//   blocks [0, nb)      : colscan  — per-(block,bucket) prefix along block axis
//   block  nb           : bscan    — exclusive scan of bucket totals -> bbase
//   blocks (nb, nb+128] : prepw    — Wt[col][k] bf16 transpose-pack of W_l2|W_r2
__global__ __launch_bounds__(256) void k_scans(const unsigned short* __restrict__ hcnt,
                                               unsigned short* __restrict__ rel,
                                               const int* __restrict__ bcnt,
                                               int* __restrict__ bbase,
                                               const float* __restrict__ Wl2,
                                               const float* __restrict__ Wr2,
                                               unsigned short* __restrict__ wt,
                                               int nblk, int nb, int E) {
  __shared__ int sm[2][256];
  int bb = blockIdx.x;
  int t = threadIdx.x;

  if (bb < nb) {
    // ---- colscan: one workgroup per bucket; thread owns entries 2t, 2t+1 ----
    int b = bb;
    int e0 = 2 * t, e1 = 2 * t + 1;
    int a = (e0 < nblk) ? (int)hcnt[(size_t)e0 * nb + b] : 0;
    int c = (e1 < nblk) ? (int)hcnt[(size_t)e1 * nb + b] : 0;
    int s = a + c;
    sm[0][t] = s;
    __syncthreads();
    int src = 0;
    for (int st = 1; st < 256; st <<= 1) {
      int v = sm[src][t];
      if (t >= st) v += sm[src][t - st];
      sm[src ^ 1][t] = v; __syncthreads(); src ^= 1;
    }
    int excl = sm[src][t] - s;
    if (e0 < nblk) rel[(size_t)e0 * nb + b] = (unsigned short)excl;
    if (e1 < nblk) rel[(size_t)e1 * nb + b] = (unsigned short)(excl + a);
  } else if (bb == nb) {
    // ---- bscan (256 threads, 4 elements each; nb <= 1024) ----
    int i0 = t * 4;
    int v0 = (i0     < nb) ? bcnt[i0]     : 0;
    int v1 = (i0 + 1 < nb) ? bcnt[i0 + 1] : 0;
    int v2 = (i0 + 2 < nb) ? bcnt[i0 + 2] : 0;
    int v3 = (i0 + 3 < nb) ? bcnt[i0 + 3] : 0;
    int s = v0 + v1 + v2 + v3;
    sm[0][t] = s;
    __syncthreads();
    int src = 0;
    for (int st = 1; st < 256; st <<= 1) {
      int v = sm[src][t];
      if (t >= st) v += sm[src][t - st];
      sm[src ^ 1][t] = v; __syncthreads(); src ^= 1;
    }
    int ex = sm[src][t] - s;
    if (i0     < nb) bbase[i0]     = ex; ex += v0;
    if (i0 + 1 < nb) bbase[i0 + 1] = ex; ex += v1;
    if (i0 + 2 < nb) bbase[i0 + 2] = ex; ex += v2;
    if (i0 + 3 < nb) bbase[i0 + 3] = ex;
    if (t == 255) bbase[nb] = E;
  } else {
    // ---- prepw: tid = c*256 + k over 128*256 ----
    int tid = (bb - nb - 1) * 256 + t;
    if (tid < 128 * 256) {
      int c = tid >> 8, k = tid & 255;
      float v = (k < 128) ? Wl2[k * 128 + c] : Wr2[(k - 128) * 128 + c];
      wt[tid] = f32_to_bf16(v);
    }
  }
}

// ---- bin pass 3: scatter packed (src<<7 | dst&127) at precomputed bases -----
__global__ __launch_bounds__(256) void k_bscatter(const int* __restrict__ ei,
                                                  const int* __restrict__ bbase,
                                                  const unsigned short* __restrict__ rel,
                                                  unsigned int* __restrict__ ebuf, int E, int nb) {
  __shared__ int h[1024];                    // in-block rank cursors
  __shared__ int base[1024];
  int t = threadIdx.x;
  const unsigned short* rr = rel + (size_t)blockIdx.x * nb;
  for (int i = t; i < nb; i += 256) {
    h[i] = 0;
    base[i] = bbase[i] + (int)rr[i];
  }
  __syncthreads();
  int tbeg = blockIdx.x * EDGE_TILE;
  int tend = min(tbeg + EDGE_TILE, E);
  const int* srcp = ei;
  const int* dstp = ei + E;
  for (int i = tbeg + t; i < tend; i += 256) {
    int d = dstp[i];
    int b = d >> 7;
    int r = atomicAdd(&h[b], 1);
    ebuf[base[b] + r] = ((unsigned)srcp[i] << 7) | (unsigned)(d & 127);
  }
}

// ---- bin pass 4: per-bucket CSR build + x-agg + FUSED layer-1 dense ---------
// After sx/deg are final this block already owns everything layer1 needs for
// its 128 nodes -> compute h16/h8 here; agg1 global roundtrip deleted (R12).
__global__ __launch_bounds__(256) void k_bucket_csr(const unsigned int* __restrict__ ebuf,
                                                    const int* __restrict__ bbase,
                                                    const float* __restrict__ x,
                                                    const float* __restrict__ Wl,
                                                    const float* __restrict__ Wr,
                                                    const float* __restrict__ b1,
                                                    int* __restrict__ offs, int* __restrict__ csr,
                                                    unsigned int* __restrict__ h16,
                                                    unsigned short* __restrict__ h8,
                                                    int N, int nb) {
  __shared__ int deg[128];
  __shared__ int loff[128];
  __shared__ int cur[128];
  __shared__ float sx0[128];
  __shared__ float sx1[128];
  int b = blockIdx.x;
  int t = threadIdx.x;
  int lo = bbase[b], hi = bbase[b + 1];
  if (t < 128) { deg[t] = 0; sx0[t] = 0.f; sx1[t] = 0.f; }
  __syncthreads();
  const float2* x2 = (const float2*)x;
  for (int i = lo + t; i < hi; i += 256) {
    unsigned int e = ebuf[i];
    int d = e & 127;
    float2 v = x2[e >> 7];
    atomicAdd(&deg[d], 1);
    atomicAdd(&sx0[d], v.x);
    atomicAdd(&sx1[d], v.y);
  }
  __syncthreads();
  if (t < 128) loff[t] = deg[t];
  __syncthreads();
  for (int st = 1; st < 128; st <<= 1) {
    int v = 0;
    if (t < 128 && t >= st) v = loff[t - st];
    __syncthreads();
    if (t < 128) loff[t] += v;
    __syncthreads();
  }
  if (t < 128) {
    int ex = loff[t] - deg[t];                 // exclusive prefix
    cur[t] = ex;
    int node = b * 128 + t;
    if (node < N) offs[node] = lo + ex;
  }
  if (b == nb - 1 && t == 0) offs[N] = hi;
  __syncthreads();
  for (int i = lo + t; i < hi; i += 256) {
    unsigned int e = ebuf[i];
    int r = atomicAdd(&cur[e & 127], 1);
    csr[lo + r] = (int)(e >> 7);
  }

  // ---- fused layer-1 dense: 128 nodes x 64 col-pairs, 32 iters/thread ----
  int nfirst = b * 128;
  for (int i = t; i < 128 * 64; i += 256) {
    int nl = i >> 6;
    int node = nfirst + nl;
    if (node >= N) break;                     // nl nondecreasing in i
    int c = (i & 63) * 2;
    int dg = deg[nl];
    float sc = 1.0f / (float)max(dg, 1);
    float a0 = sx0[nl] * sc, a1 = sx1[nl] * sc;
    float2 xv = x2[node];
    float r0 = fmaf(a0, Wl[c],     fmaf(a1, Wl[128 + c],     fmaf(xv.x, Wr[c],     fmaf(xv.y, Wr[128 + c],     b1[c]))));
    float r1 = fmaf(a0, Wl[c + 1], fmaf(a1, Wl[128 + c + 1], fmaf(xv.x, Wr[c + 1], fmaf(xv.y, Wr[128 + c + 1], b1[c + 1]))));
    r0 = r0 > 0.f ? r0 : 0.f;
    r1 = r1 > 0.f ? r1 : 0.f;
    unsigned int packed = (unsigned int)f32_to_bf16(r0) | ((unsigned int)f32_to_bf16(r1) << 16);
    h16[(size_t)node * 64 + (i & 63)] = packed;
    unsigned int p8 = (unsigned int)__builtin_amdgcn_cvt_pk_fp8_f32(r0, r1, 0, false);
    h8[(size_t)node * 64 + (i & 63)] = (unsigned short)(p8 & 0xffffu);
  }
}

// ---- layer-2 aggregation: 8 nodes/wave, 8 lanes/node, 16 cols/lane ----------
// R12: cross-iteration prefetch — rows (t,t+1) load while (t-2,t-1) ACC8.
#define ACC8(v)                                                                              \
  do {                                                                                       \
    f32x2 p;                                                                                 \
    p = __builtin_amdgcn_cvt_pk_f32_fp8((int)(v).x, false); acc[0] += p[0];  acc[1] += p[1]; \
    p = __builtin_amdgcn_cvt_pk_f32_fp8((int)(v).x, true);  acc[2] += p[0];  acc[3] += p[1]; \
    p = __builtin_amdgcn_cvt_pk_f32_fp8((int)(v).y, false); acc[4] += p[0];  acc[5] += p[1]; \
    p = __builtin_amdgcn_cvt_pk_f32_fp8((int)(v).y, true);  acc[6] += p[0];  acc[7] += p[1]; \
    p = __builtin_amdgcn_cvt_pk_f32_fp8((int)(v).z, false); acc[8] += p[0];  acc[9] += p[1]; \
    p = __builtin_amdgcn_cvt_pk_f32_fp8((int)(v).z, true);  acc[10] += p[0]; acc[11] += p[1];\
    p = __builtin_amdgcn_cvt_pk_f32_fp8((int)(v).w, false); acc[12] += p[0]; acc[13] += p[1];\
    p = __builtin_amdgcn_cvt_pk_f32_fp8((int)(v).w, true);  acc[14] += p[0]; acc[15] += p[1];\
  } while (0)

__global__ __launch_bounds__(256) void k_agg2(const int* __restrict__ offs, const int* __restrict__ csr,
                                              const unsigned char* __restrict__ h8,
                                              unsigned int* __restrict__ a16, int n) {
  int wv   = threadIdx.x >> 6;
  int lane = threadIdx.x & 63;
  int sub  = lane >> 3;          // node slot within wave: 0..7
  int cb   = lane & 7;           // 16-col block: cols cb*16 .. cb*16+15
  int node = blockIdx.x * 32 + wv * 8 + sub;
  if (node >= n) return;
  int beg = offs[node];
  int end = offs[node + 1];
  int deg = end - beg;
  const unsigned char* hb = h8 + cb * 16;

  float acc[16];
#pragma unroll
  for (int j = 0; j < 16; ++j) acc[j] = 0.f;

  int t = 0;
  if (deg >= 2) {
    int s0 = csr[beg];
    int s1 = csr[beg + 1];
    uint4 c0 = *(const uint4*)(hb + (size_t)s0 * 128);
    uint4 c1 = *(const uint4*)(hb + (size_t)s1 * 128);
    for (t = 2; t + 1 < deg; t += 2) {
      int n0 = csr[beg + t];
      int n1 = csr[beg + t + 1];
      uint4 p0 = *(const uint4*)(hb + (size_t)n0 * 128);   // prefetch next pair
      uint4 p1 = *(const uint4*)(hb + (size_t)n1 * 128);
      ACC8(c0);
      ACC8(c1);
      c0 = p0; c1 = p1;
    }
    ACC8(c0);
    ACC8(c1);
  }
  if (t < deg) {
    int s0 = csr[beg + t];
    uint4 v0 = *(const uint4*)(hb + (size_t)s0 * 128);
    ACC8(v0);
  }

  float scale = 1.0f / (float)max(deg, 1);
  unsigned int u[8];
#pragma unroll
  for (int k = 0; k < 8; ++k)
    u[k] = (unsigned int)f32_to_bf16(acc[2 * k] * scale) |
           ((unsigned int)f32_to_bf16(acc[2 * k + 1] * scale) << 16);
  unsigned int* dst = a16 + (size_t)node * 64 + cb * 8;   // row = 64 uints
  *(uint4*)dst       = make_uint4(u[0], u[1], u[2], u[3]);
  *(uint4*)(dst + 4) = make_uint4(u[4], u[5], u[6], u[7]);
}

// ---- layer-2 GEMM: out[N,128] = [agg2|h](bf16) @ Wt(bf16) + b2, MFMA --------
__global__ __launch_bounds__(256) void k_gemm(const unsigned short* __restrict__ a16,
                                              const unsigned short* __restrict__ h16,
                                              const unsigned short* __restrict__ wt,
                                              const float* __restrict__ b2,
                                              float* __restrict__ out, int nrows) {
  __shared__ unsigned short bs[64 * 264];   // 33792 B
  int half = blockIdx.x & 1;
  int tg   = blockIdx.x >> 1;

#pragma unroll
  for (int i = 0; i < 8; ++i) {
    int c = threadIdx.x + i * 256;          // 0..2047
    int row = c >> 5, off = c & 31;         // off in 16B units
    *(uint4*)(bs + row * 264 + off * 8) =
        *(const uint4*)(wt + ((size_t)(half * 64 + row)) * 256 + off * 8);
  }
  __syncthreads();

  int wv   = threadIdx.x >> 6;
  int lane = threadIdx.x & 63;
  int m16 = lane & 15, quad = lane >> 4;
  int tile = tg * 4 + wv;
  if (tile * 16 >= nrows) return;

  int r  = tile * 16 + m16;
  int rc = r < nrows ? r : nrows - 1;
  const unsigned short* arow = a16 + (size_t)rc * 128 + quad * 8;
  const unsigned short* hrow = h16 + (size_t)rc * 128 + quad * 8;

  s16x8 afrag[8];
#pragma unroll
  for (int c4 = 0; c4 < 4; ++c4) {
    afrag[c4]     = *(const s16x8*)(arow + c4 * 32);   // A[m][k], k-chunk c4
    afrag[4 + c4] = *(const s16x8*)(hrow + c4 * 32);
  }

  f32x4 acc[4];
#pragma unroll
  for (int t = 0; t < 4; ++t) acc[t] = (f32x4){0.f, 0.f, 0.f, 0.f};

  const unsigned short* bbase = bs + m16 * 264 + quad * 8;
#pragma unroll
  for (int ch = 0; ch < 8; ++ch) {
#pragma unroll
    for (int t = 0; t < 4; ++t) {
      s16x8 bf = *(const s16x8*)(bbase + t * 16 * 264 + ch * 32); // B[k][n]
      acc[t] = __builtin_amdgcn_mfma_f32_16x16x32_bf16(afrag[ch], bf, acc[t], 0, 0, 0);
    }
  }

#pragma unroll
  for (int t = 0; t < 4; ++t) {
    int col = half * 64 + t * 16 + m16;
    float bias = b2[col];
#pragma unroll
    for (int i = 0; i < 4; ++i) {
      int row = tile * 16 + quad * 4 + i;   // C/D: col=lane&15, row=quad*4+reg
      if (row < nrows) out[(size_t)row * 128 + col] = acc[t][i] + bias;
    }
  }
}

// ---------------------------------------------------------------------------
extern "C" void kernel_launch(void* const* d_in, const int* in_sizes, int n_in,
                              void* d_out, int out_size, void* d_ws, size_t ws_size,
                              hipStream_t stream) {
  const float* x    = (const float*)d_in[0];
  const int*   ei   = (const int*)d_in[1];
  const float* Wl1  = (const float*)d_in[2];
  const float* Wr1  = (const float*)d_in[3];
  const float* b1   = (const float*)d_in[4];
  const float* Wl2  = (const float*)d_in[5];
  const float* Wr2  = (const float*)d_in[6];
  const float* b2   = (const float*)d_in[7];
  float* out = (float*)d_out;

  const int N = in_sizes[0] / 2;     // 100000
  const int E = in_sizes[1] / 2;     // 1600000
  const int nb = (N + 127) >> 7;     // 782 buckets
  const int nblk_e = (E + EDGE_TILE - 1) / EDGE_TILE;   // 391

  // workspace carve-up (256B aligned)
  char* p = (char*)d_ws;
  auto take = [&](size_t bytes) { char* r = p; p += (bytes + 255) & ~(size_t)255; return r; };
  int* bcnt            = (int*)take(1024 * 4);
  int* bbase           = (int*)take(1025 * 4);
  unsigned short* hcnt = (unsigned short*)take((size_t)nblk_e * nb * 2);
  unsigned short* rel  = (unsigned short*)take((size_t)nblk_e * nb * 2);
  int* offs            = (int*)take((size_t)(N + 1) * 4);
  int* csr             = (int*)take((size_t)E * 4);
  unsigned int* ebuf   = (unsigned int*)take((size_t)E * 4);
  unsigned short* h16  = (unsigned short*)take((size_t)N * 128 * 2);
  unsigned short* a16  = (unsigned short*)take((size_t)N * 128 * 2);
  unsigned short* h8   = (unsigned short*)take((size_t)N * 128);
  unsigned short* wt   = (unsigned short*)take((size_t)128 * 256 * 2);

  const int ntiles = (N + 15) / 16;                      // 6250

  hipMemsetAsync(bcnt, 0, 1024 * 4, stream);

  k_bhist     <<<nblk_e, 256, 0, stream>>>(ei, bcnt, hcnt, E, nb);
  k_scans     <<<nb + 1 + 128, 256, 0, stream>>>(hcnt, rel, bcnt, bbase, Wl2, Wr2, wt,
                                                 nblk_e, nb, E);
  k_bscatter  <<<nblk_e, 256, 0, stream>>>(ei, bbase, rel, ebuf, E, nb);
  k_bucket_csr<<<nb, 256, 0, stream>>>(ebuf, bbase, x, Wl1, Wr1, b1, offs, csr,
                                       (unsigned int*)h16, h8, N, nb);
  k_agg2      <<<(N + 31) / 32, 256, 0, stream>>>(offs, csr, (const unsigned char*)h8,
                                                  (unsigned int*)a16, N);
  k_gemm      <<<((ntiles + 3) / 4) * 2, 256, 0, stream>>>(a16, h16, wt, b2, out, N);
}

// Round 7
// 240.555 us; speedup vs baseline: 1.1574x; 1.0061x over previous
//
#include <hip/hip_runtime.h>

// ---------------------------------------------------------------------------
// GraphSAGE 2-layer, mean aggregation.
//   L1: h = relu( mean_nbr(x) @ W_l1 + x @ W_r1 + b1 )   (IN=2 -> aggregate x first)
//   L2: out = mean_nbr(h) @ W_l2 + h @ W_r2 + b2
// R2: CSR via 2-level MSD binning (bucket = dst>>7).
// R4: layer-2 aggregation gathers h in fp8 e4m3.
// R6: agg2: 8 nodes/wave, 8 lanes/node, 16 cols/lane.
// R7: FAILED global counting sort (1-block scan 233us; random device atomics).
// R8: NEUTRAL XCD-seg ebuf. Reverted.
// R9/R10: bscatter pass-1 eliminated (per-(block,bucket) bases + parallel
//     colscan). 246.3us.
// R11: FAILED agg2+gemm fusion (barrier couples waves to degree straggler).
// R12: 7 dispatches: k_scans (colscan|bscan|prepw by blockIdx); layer1 folded
//     into k_bucket_csr; agg2 cross-iteration prefetch. 242.0us.
// R13: k_bucket_csr restructured (57us @ 11% HBM, 12% VALU, 24% occ,
//     253K LDS conflicts -> latency-bound on 3-atomic+gather edge chain):
//     pass1 = deg-only int atomic (no x gather, no float atomics);
//     pass3 (new) = per-node x-sum over CONTIGUOUS csr range, 2 threads/node,
//     8 independent gathers deep, shfl_xor combine, plain sx stores.
// ---------------------------------------------------------------------------

using f32x4 = __attribute__((ext_vector_type(4))) float;
using f32x2 = __attribute__((ext_vector_type(2))) float;
using s16x8 = __attribute__((ext_vector_type(8))) short;

__device__ __forceinline__ unsigned short f32_to_bf16(float f) {
  unsigned int u = __float_as_uint(f);
  u += 0x7fffu + ((u >> 16) & 1u);          // round-to-nearest-even
  return (unsigned short)(u >> 16);
}

#define EDGE_TILE 4096

// ---- bin pass 1: bucket histogram; stores per-block row + bucket totals -----
__global__ __launch_bounds__(256) void k_bhist(const int* __restrict__ ei, int* __restrict__ bcnt,
                                               unsigned short* __restrict__ hcnt, int E, int nb) {
  __shared__ int h[1024];
  int t = threadIdx.x;
  for (int i = t; i < nb; i += 256) h[i] = 0;
  __syncthreads();
  int tbeg = blockIdx.x * EDGE_TILE;
  int tend = min(tbeg + EDGE_TILE, E);
  const int* dstp = ei + E;
  for (int i = tbeg + t; i < tend; i += 256) atomicAdd(&h[dstp[i] >> 7], 1);
  __syncthreads();
  unsigned short* hr = hcnt + (size_t)blockIdx.x * nb;
  for (int i = t; i < nb; i += 256) {
    int c = h[i];
    hr[i] = (unsigned short)c;              // c <= EDGE_TILE=4096, fits u16
    if (c) atomicAdd(&bcnt[i], c);
  }
}

// ---- pass 2 (ONE launch, role by blockIdx):
//   blocks [0, nb)      : colscan  — per-(block,bucket) prefix along block axis
//   block  nb           : bscan    — exclusive scan of bucket totals -> bbase
//   blocks (nb, nb+128] : prepw    — Wt[col][k] bf16 transpose-pack of W_l2|W_r2
__global__ __launch_bounds__(256) void k_scans(const unsigned short* __restrict__ hcnt,
                                               unsigned short* __restrict__ rel,
                                               const int* __restrict__ bcnt,
                                               int* __restrict__ bbase,
                                               const float* __restrict__ Wl2,
                                               const float* __restrict__ Wr2,
                                               unsigned short* __restrict__ wt,
                                               int nblk, int nb, int E) {
  __shared__ int sm[2][256];
  int bb = blockIdx.x;
  int t = threadIdx.x;

  if (bb < nb) {
    // ---- colscan: one workgroup per bucket; thread owns entries 2t, 2t+1 ----
    int b = bb;
    int e0 = 2 * t, e1 = 2 * t + 1;
    int a = (e0 < nblk) ? (int)hcnt[(size_t)e0 * nb + b] : 0;
    int c = (e1 < nblk) ? (int)hcnt[(size_t)e1 * nb + b] : 0;
    int s = a + c;
    sm[0][t] = s;
    __syncthreads();
    int src = 0;
    for (int st = 1; st < 256; st <<= 1) {
      int v = sm[src][t];
      if (t >= st) v += sm[src][t - st];
      sm[src ^ 1][t] = v; __syncthreads(); src ^= 1;
    }
    int excl = sm[src][t] - s;
    if (e0 < nblk) rel[(size_t)e0 * nb + b] = (unsigned short)excl;
    if (e1 < nblk) rel[(size_t)e1 * nb + b] = (unsigned short)(excl + a);
  } else if (bb == nb) {
    // ---- bscan (256 threads, 4 elements each; nb <= 1024) ----
    int i0 = t * 4;
    int v0 = (i0     < nb) ? bcnt[i0]     : 0;
    int v1 = (i0 + 1 < nb) ? bcnt[i0 + 1] : 0;
    int v2 = (i0 + 2 < nb) ? bcnt[i0 + 2] : 0;
    int v3 = (i0 + 3 < nb) ? bcnt[i0 + 3] : 0;
    int s = v0 + v1 + v2 + v3;
    sm[0][t] = s;
    __syncthreads();
    int src = 0;
    for (int st = 1; st < 256; st <<= 1) {
      int v = sm[src][t];
      if (t >= st) v += sm[src][t - st];
      sm[src ^ 1][t] = v; __syncthreads(); src ^= 1;
    }
    int ex = sm[src][t] - s;
    if (i0     < nb) bbase[i0]     = ex; ex += v0;
    if (i0 + 1 < nb) bbase[i0 + 1] = ex; ex += v1;
    if (i0 + 2 < nb) bbase[i0 + 2] = ex; ex += v2;
    if (i0 + 3 < nb) bbase[i0 + 3] = ex;
    if (t == 255) bbase[nb] = E;
  } else {
    // ---- prepw: tid = c*256 + k over 128*256 ----
    int tid = (bb - nb - 1) * 256 + t;
    if (tid < 128 * 256) {
      int c = tid >> 8, k = tid & 255;
      float v = (k < 128) ? Wl2[k * 128 + c] : Wr2[(k - 128) * 128 + c];
      wt[tid] = f32_to_bf16(v);
    }
  }
}

// ---- bin pass 3: scatter packed (src<<7 | dst&127) at precomputed bases -----
__global__ __launch_bounds__(256) void k_bscatter(const int* __restrict__ ei,
                                                  const int* __restrict__ bbase,
                                                  const unsigned short* __restrict__ rel,
                                                  unsigned int* __restrict__ ebuf, int E, int nb) {
  __shared__ int h[1024];                    // in-block rank cursors
  __shared__ int base[1024];
  int t = threadIdx.x;
  const unsigned short* rr = rel + (size_t)blockIdx.x * nb;
  for (int i = t; i < nb; i += 256) {
    h[i] = 0;
    base[i] = bbase[i] + (int)rr[i];
  }
  __syncthreads();
  int tbeg = blockIdx.x * EDGE_TILE;
  int tend = min(tbeg + EDGE_TILE, E);
  const int* srcp = ei;
  const int* dstp = ei + E;
  for (int i = tbeg + t; i < tend; i += 256) {
    int d = dstp[i];
    int b = d >> 7;
    int r = atomicAdd(&h[b], 1);
    ebuf[base[b] + r] = ((unsigned)srcp[i] << 7) | (unsigned)(d & 127);
  }
}

// ---- bin pass 4: per-bucket CSR build + x-agg (post-csr) + layer-1 dense ----
// R13: pass1 deg-only int atomics; x-sum moved AFTER csr build where each
// node's edges are contiguous (2 threads/node, independent gathers, no
// atomics); layer1 dense epilogue unchanged.
__global__ __launch_bounds__(256) void k_bucket_csr(const unsigned int* __restrict__ ebuf,
                                                    const int* __restrict__ bbase,
                                                    const float* __restrict__ x,
                                                    const float* __restrict__ Wl,
                                                    const float* __restrict__ Wr,
                                                    const float* __restrict__ b1,
                                                    int* __restrict__ offs, int* __restrict__ csr,
                                                    unsigned int* __restrict__ h16,
                                                    unsigned short* __restrict__ h8,
                                                    int N, int nb) {
  __shared__ int deg[128];
  __shared__ int loff[128];
  __shared__ int exo[128];
  __shared__ int cur[128];
  __shared__ float sx0[128];
  __shared__ float sx1[128];
  int b = blockIdx.x;
  int t = threadIdx.x;
  int lo = bbase[b], hi = bbase[b + 1];
  if (t < 128) deg[t] = 0;
  __syncthreads();

  // pass 1: degree histogram only (1 int atomic per edge)
  for (int i = lo + t; i < hi; i += 256) atomicAdd(&deg[ebuf[i] & 127], 1);
  __syncthreads();

  // scan degrees -> exclusive offsets
  if (t < 128) loff[t] = deg[t];
  __syncthreads();
  for (int st = 1; st < 128; st <<= 1) {
    int v = 0;
    if (t < 128 && t >= st) v = loff[t - st];
    __syncthreads();
    if (t < 128) loff[t] += v;
    __syncthreads();
  }
  if (t < 128) {
    int ex = loff[t] - deg[t];                 // exclusive prefix
    exo[t] = ex;
    cur[t] = ex;
    int node = b * 128 + t;
    if (node < N) offs[node] = lo + ex;
  }
  if (b == nb - 1 && t == 0) offs[N] = hi;
  __syncthreads();

  // pass 2: rank-scatter into csr (node-sorted within bucket)
  for (int i = lo + t; i < hi; i += 256) {
    unsigned int e = ebuf[i];
    int r = atomicAdd(&cur[e & 127], 1);
    csr[lo + r] = (int)(e >> 7);
  }
  __syncthreads();

  // pass 3: per-node x-sum over contiguous csr range (2 threads/node)
  const float2* x2 = (const float2*)x;
  {
    int nl = t >> 1;                          // 0..127
    int node = b * 128 + nl;
    float ax = 0.f, ay = 0.f;
    if (node < N) {
      int base = lo + exo[nl];
      int dg = deg[nl];
      for (int j = (t & 1); j < dg; j += 2) {
        float2 v = x2[csr[base + j]];
        ax += v.x;
        ay += v.y;
      }
    }
    ax += __shfl_xor(ax, 1);
    ay += __shfl_xor(ay, 1);
    if ((t & 1) == 0) { sx0[nl] = ax; sx1[nl] = ay; }
  }
  __syncthreads();

  // layer-1 dense: 128 nodes x 64 col-pairs, 32 iters/thread
  int nfirst = b * 128;
  for (int i = t; i < 128 * 64; i += 256) {
    int nl = i >> 6;
    int node = nfirst + nl;
    if (node >= N) break;                     // nl nondecreasing in i
    int c = (i & 63) * 2;
    int dg = deg[nl];
    float sc = 1.0f / (float)max(dg, 1);
    float a0 = sx0[nl] * sc, a1 = sx1[nl] * sc;
    float2 xv = x2[node];
    float r0 = fmaf(a0, Wl[c],     fmaf(a1, Wl[128 + c],     fmaf(xv.x, Wr[c],     fmaf(xv.y, Wr[128 + c],     b1[c]))));
    float r1 = fmaf(a0, Wl[c + 1], fmaf(a1, Wl[128 + c + 1], fmaf(xv.x, Wr[c + 1], fmaf(xv.y, Wr[128 + c + 1], b1[c + 1]))));
    r0 = r0 > 0.f ? r0 : 0.f;
    r1 = r1 > 0.f ? r1 : 0.f;
    unsigned int packed = (unsigned int)f32_to_bf16(r0) | ((unsigned int)f32_to_bf16(r1) << 16);
    h16[(size_t)node * 64 + (i & 63)] = packed;
    unsigned int p8 = (unsigned int)__builtin_amdgcn_cvt_pk_fp8_f32(r0, r1, 0, false);
    h8[(size_t)node * 64 + (i & 63)] = (unsigned short)(p8 & 0xffffu);
  }
}

// ---- layer-2 aggregation: 8 nodes/wave, 8 lanes/node, 16 cols/lane ----------
// R12: cross-iteration prefetch — rows (t,t+1) load while (t-2,t-1) ACC8.
#define ACC8(v)                                                                              \
  do {                                                                                       \
    f32x2 p;                                                                                 \
    p = __builtin_amdgcn_cvt_pk_f32_fp8((int)(v).x, false); acc[0] += p[0];  acc[1] += p[1]; \
    p = __builtin_amdgcn_cvt_pk_f32_fp8((int)(v).x, true);  acc[2] += p[0];  acc[3] += p[1]; \
    p = __builtin_amdgcn_cvt_pk_f32_fp8((int)(v).y, false); acc[4] += p[0];  acc[5] += p[1]; \
    p = __builtin_amdgcn_cvt_pk_f32_fp8((int)(v).y, true);  acc[6] += p[0];  acc[7] += p[1]; \
    p = __builtin_amdgcn_cvt_pk_f32_fp8((int)(v).z, false); acc[8] += p[0];  acc[9] += p[1]; \
    p = __builtin_amdgcn_cvt_pk_f32_fp8((int)(v).z, true);  acc[10] += p[0]; acc[11] += p[1];\
    p = __builtin_amdgcn_cvt_pk_f32_fp8((int)(v).w, false); acc[12] += p[0]; acc[13] += p[1];\
    p = __builtin_amdgcn_cvt_pk_f32_fp8((int)(v).w, true);  acc[14] += p[0]; acc[15] += p[1];\
  } while (0)

__global__ __launch_bounds__(256) void k_agg2(const int* __restrict__ offs, const int* __restrict__ csr,
                                              const unsigned char* __restrict__ h8,
                                              unsigned int* __restrict__ a16, int n) {
  int wv   = threadIdx.x >> 6;
  int lane = threadIdx.x & 63;
  int sub  = lane >> 3;          // node slot within wave: 0..7
  int cb   = lane & 7;           // 16-col block: cols cb*16 .. cb*16+15
  int node = blockIdx.x * 32 + wv * 8 + sub;
  if (node >= n) return;
  int beg = offs[node];
  int end = offs[node + 1];
  int deg = end - beg;
  const unsigned char* hb = h8 + cb * 16;

  float acc[16];
#pragma unroll
  for (int j = 0; j < 16; ++j) acc[j] = 0.f;

  int t = 0;
  if (deg >= 2) {
    int s0 = csr[beg];
    int s1 = csr[beg + 1];
    uint4 c0 = *(const uint4*)(hb + (size_t)s0 * 128);
    uint4 c1 = *(const uint4*)(hb + (size_t)s1 * 128);
    for (t = 2; t + 1 < deg; t += 2) {
      int n0 = csr[beg + t];
      int n1 = csr[beg + t + 1];
      uint4 p0 = *(const uint4*)(hb + (size_t)n0 * 128);   // prefetch next pair
      uint4 p1 = *(const uint4*)(hb + (size_t)n1 * 128);
      ACC8(c0);
      ACC8(c1);
      c0 = p0; c1 = p1;
    }
    ACC8(c0);
    ACC8(c1);
  }
  if (t < deg) {
    int s0 = csr[beg + t];
    uint4 v0 = *(const uint4*)(hb + (size_t)s0 * 128);
    ACC8(v0);
  }

  float scale = 1.0f / (float)max(deg, 1);
  unsigned int u[8];
#pragma unroll
  for (int k = 0; k < 8; ++k)
    u[k] = (unsigned int)f32_to_bf16(acc[2 * k] * scale) |
           ((unsigned int)f32_to_bf16(acc[2 * k + 1] * scale) << 16);
  unsigned int* dst = a16 + (size_t)node * 64 + cb * 8;   // row = 64 uints
  *(uint4*)dst       = make_uint4(u[0], u[1], u[2], u[3]);
  *(uint4*)(dst + 4) = make_uint4(u[4], u[5], u[6], u[7]);
}

// ---- layer-2 GEMM: out[N,128] = [agg2|h](bf16) @ Wt(bf16) + b2, MFMA --------
__global__ __launch_bounds__(256) void k_gemm(const unsigned short* __restrict__ a16,
                                              const unsigned short* __restrict__ h16,
                                              const unsigned short* __restrict__ wt,
                                              const float* __restrict__ b2,
                                              float* __restrict__ out, int nrows) {
  __shared__ unsigned short bs[64 * 264];   // 33792 B
  int half = blockIdx.x & 1;
  int tg   = blockIdx.x >> 1;

#pragma unroll
  for (int i = 0; i < 8; ++i) {
    int c = threadIdx.x + i * 256;          // 0..2047
    int row = c >> 5, off = c & 31;         // off in 16B units
    *(uint4*)(bs + row * 264 + off * 8) =
        *(const uint4*)(wt + ((size_t)(half * 64 + row)) * 256 + off * 8);
  }
  __syncthreads();

  int wv   = threadIdx.x >> 6;
  int lane = threadIdx.x & 63;
  int m16 = lane & 15, quad = lane >> 4;
  int tile = tg * 4 + wv;
  if (tile * 16 >= nrows) return;

  int r  = tile * 16 + m16;
  int rc = r < nrows ? r : nrows - 1;
  const unsigned short* arow = a16 + (size_t)rc * 128 + quad * 8;
  const unsigned short* hrow = h16 + (size_t)rc * 128 + quad * 8;

  s16x8 afrag[8];
#pragma unroll
  for (int c4 = 0; c4 < 4; ++c4) {
    afrag[c4]     = *(const s16x8*)(arow + c4 * 32);   // A[m][k], k-chunk c4
    afrag[4 + c4] = *(const s16x8*)(hrow + c4 * 32);
  }

  f32x4 acc[4];
#pragma unroll
  for (int t = 0; t < 4; ++t) acc[t] = (f32x4){0.f, 0.f, 0.f, 0.f};

  const unsigned short* bbase = bs + m16 * 264 + quad * 8;
#pragma unroll
  for (int ch = 0; ch < 8; ++ch) {
#pragma unroll
    for (int t = 0; t < 4; ++t) {
      s16x8 bf = *(const s16x8*)(bbase + t * 16 * 264 + ch * 32); // B[k][n]
      acc[t] = __builtin_amdgcn_mfma_f32_16x16x32_bf16(afrag[ch], bf, acc[t], 0, 0, 0);
    }
  }

#pragma unroll
  for (int t = 0; t < 4; ++t) {
    int col = half * 64 + t * 16 + m16;
    float bias = b2[col];
#pragma unroll
    for (int i = 0; i < 4; ++i) {
      int row = tile * 16 + quad * 4 + i;   // C/D: col=lane&15, row=quad*4+reg
      if (row < nrows) out[(size_t)row * 128 + col] = acc[t][i] + bias;
    }
  }
}

// ---------------------------------------------------------------------------
extern "C" void kernel_launch(void* const* d_in, const int* in_sizes, int n_in,
                              void* d_out, int out_size, void* d_ws, size_t ws_size,
                              hipStream_t stream) {
  const float* x    = (const float*)d_in[0];
  const int*   ei   = (const int*)d_in[1];
  const float* Wl1  = (const float*)d_in[2];
  const float* Wr1  = (const float*)d_in[3];
  const float* b1   = (const float*)d_in[4];
  const float* Wl2  = (const float*)d_in[5];
  const float* Wr2  = (const float*)d_in[6];
  const float* b2   = (const float*)d_in[7];
  float* out = (float*)d_out;

  const int N = in_sizes[0] / 2;     // 100000
  const int E = in_sizes[1] / 2;     // 1600000
  const int nb = (N + 127) >> 7;     // 782 buckets
  const int nblk_e = (E + EDGE_TILE - 1) / EDGE_TILE;   // 391

  // workspace carve-up (256B aligned)
  char* p = (char*)d_ws;
  auto take = [&](size_t bytes) { char* r = p; p += (bytes + 255) & ~(size_t)255; return r; };
  int* bcnt            = (int*)take(1024 * 4);
  int* bbase           = (int*)take(1025 * 4);
  unsigned short* hcnt = (unsigned short*)take((size_t)nblk_e * nb * 2);
  unsigned short* rel  = (unsigned short*)take((size_t)nblk_e * nb * 2);
  int* offs            = (int*)take((size_t)(N + 1) * 4);
  int* csr             = (int*)take((size_t)E * 4);
  unsigned int* ebuf   = (unsigned int*)take((size_t)E * 4);
  unsigned short* h16  = (unsigned short*)take((size_t)N * 128 * 2);
  unsigned short* a16  = (unsigned short*)take((size_t)N * 128 * 2);
  unsigned short* h8   = (unsigned short*)take((size_t)N * 128);
  unsigned short* wt   = (unsigned short*)take((size_t)128 * 256 * 2);

  const int ntiles = (N + 15) / 16;                      // 6250

  hipMemsetAsync(bcnt, 0, 1024 * 4, stream);

  k_bhist     <<<nblk_e, 256, 0, stream>>>(ei, bcnt, hcnt, E, nb);
  k_scans     <<<nb + 1 + 128, 256, 0, stream>>>(hcnt, rel, bcnt, bbase, Wl2, Wr2, wt,
                                                 nblk_e, nb, E);
  k_bscatter  <<<nblk_e, 256, 0, stream>>>(ei, bbase, rel, ebuf, E, nb);
  k_bucket_csr<<<nb, 256, 0, stream>>>(ebuf, bbase, x, Wl1, Wr1, b1, offs, csr,
                                       (unsigned int*)h16, h8, N, nb);
  k_agg2      <<<(N + 31) / 32, 256, 0, stream>>>(offs, csr, (const unsigned char*)h8,
                                                  (unsigned int*)a16, N);
  k_gemm      <<<((ntiles + 3) / 4) * 2, 256, 0, stream>>>(a16, h16, wt, b2, out, N);
}

// Round 8
// 235.741 us; speedup vs baseline: 1.1811x; 1.0204x over previous
//
#include <hip/hip_runtime.h>

// ---------------------------------------------------------------------------
// GraphSAGE 2-layer, mean aggregation.
//   L1: h = relu( mean_nbr(x) @ W_l1 + x @ W_r1 + b1 )   (IN=2 -> aggregate x first)
//   L2: out = mean_nbr(h) @ W_l2 + h @ W_r2 + b2
// R2: CSR via 2-level MSD binning.
// R4: layer-2 aggregation gathers h in fp8 e4m3.
// R6: agg2: 8 nodes/wave, 8 lanes/node, 16 cols/lane.
// R7: FAILED global counting sort. R8: NEUTRAL XCD-seg ebuf.
// R9/R10: bscatter pass-1 eliminated (per-(block,bucket) bases + parallel
//     colscan). R11: FAILED agg2+gemm fusion (degree straggler).
// R12: 7 dispatches: k_scans (colscan|bscan|prepw); layer1 folded into
//     k_bucket_csr; agg2 cross-iteration prefetch. 242.0us.
// R13: bucket_csr: deg-only pass1, x-sum over contiguous csr (post-build).
//     240.6us; bucket_csr 50us @ 23.7% occ — grid-limited (782 blocks).
// R14: bucket = dst>>6 (64 nodes) -> nb=1563 blocks, 2x wave parallelism in
//     bucket_csr (the falsifier's branch: occupancy, not atomics, is the
//     constraint). ebuf pack = (src<<6)|(dst&63); bhist/bscatter LDS 1600
//     slots; bscan 8 elems/thread; pass3 4 threads/node.
// ---------------------------------------------------------------------------

using f32x4 = __attribute__((ext_vector_type(4))) float;
using f32x2 = __attribute__((ext_vector_type(2))) float;
using s16x8 = __attribute__((ext_vector_type(8))) short;

__device__ __forceinline__ unsigned short f32_to_bf16(float f) {
  unsigned int u = __float_as_uint(f);
  u += 0x7fffu + ((u >> 16) & 1u);          // round-to-nearest-even
  return (unsigned short)(u >> 16);
}

#define EDGE_TILE 4096
#define NBMAX 1600

// ---- bin pass 1: bucket histogram; stores per-block row + bucket totals -----
__global__ __launch_bounds__(256) void k_bhist(const int* __restrict__ ei, int* __restrict__ bcnt,
                                               unsigned short* __restrict__ hcnt, int E, int nb) {
  __shared__ int h[NBMAX];
  int t = threadIdx.x;
  for (int i = t; i < nb; i += 256) h[i] = 0;
  __syncthreads();
  int tbeg = blockIdx.x * EDGE_TILE;
  int tend = min(tbeg + EDGE_TILE, E);
  const int* dstp = ei + E;
  for (int i = tbeg + t; i < tend; i += 256) atomicAdd(&h[dstp[i] >> 6], 1);
  __syncthreads();
  unsigned short* hr = hcnt + (size_t)blockIdx.x * nb;
  for (int i = t; i < nb; i += 256) {
    int c = h[i];
    hr[i] = (unsigned short)c;              // c <= EDGE_TILE=4096, fits u16
    if (c) atomicAdd(&bcnt[i], c);
  }
}

// ---- pass 2 (ONE launch, role by blockIdx):
//   blocks [0, nb)      : colscan  — per-(block,bucket) prefix along block axis
//   block  nb           : bscan    — exclusive scan of bucket totals -> bbase
//   blocks (nb, nb+128] : prepw    — Wt[col][k] bf16 transpose-pack of W_l2|W_r2
__global__ __launch_bounds__(256) void k_scans(const unsigned short* __restrict__ hcnt,
                                               unsigned short* __restrict__ rel,
                                               const int* __restrict__ bcnt,
                                               int* __restrict__ bbase,
                                               const float* __restrict__ Wl2,
                                               const float* __restrict__ Wr2,
                                               unsigned short* __restrict__ wt,
                                               int nblk, int nb, int E) {
  __shared__ int sm[2][256];
  int bb = blockIdx.x;
  int t = threadIdx.x;

  if (bb < nb) {
    // ---- colscan: one workgroup per bucket; thread owns entries 2t, 2t+1 ----
    int b = bb;
    int e0 = 2 * t, e1 = 2 * t + 1;
    int a = (e0 < nblk) ? (int)hcnt[(size_t)e0 * nb + b] : 0;
    int c = (e1 < nblk) ? (int)hcnt[(size_t)e1 * nb + b] : 0;
    int s = a + c;
    sm[0][t] = s;
    __syncthreads();
    int src = 0;
    for (int st = 1; st < 256; st <<= 1) {
      int v = sm[src][t];
      if (t >= st) v += sm[src][t - st];
      sm[src ^ 1][t] = v; __syncthreads(); src ^= 1;
    }
    int excl = sm[src][t] - s;
    if (e0 < nblk) rel[(size_t)e0 * nb + b] = (unsigned short)excl;
    if (e1 < nblk) rel[(size_t)e1 * nb + b] = (unsigned short)(excl + a);
  } else if (bb == nb) {
    // ---- bscan (256 threads, 8 elements each; nb <= 2048) ----
    int i0 = t * 8;
    int v[8];
    int s = 0;
#pragma unroll
    for (int j = 0; j < 8; ++j) {
      v[j] = (i0 + j < nb) ? bcnt[i0 + j] : 0;
      s += v[j];
    }
    sm[0][t] = s;
    __syncthreads();
    int src = 0;
    for (int st = 1; st < 256; st <<= 1) {
      int vv = sm[src][t];
      if (t >= st) vv += sm[src][t - st];
      sm[src ^ 1][t] = vv; __syncthreads(); src ^= 1;
    }
    int ex = sm[src][t] - s;
#pragma unroll
    for (int j = 0; j < 8; ++j) {
      if (i0 + j < nb) bbase[i0 + j] = ex;
      ex += v[j];
    }
    if (t == 255) bbase[nb] = E;
  } else {
    // ---- prepw: tid = c*256 + k over 128*256 ----
    int tid = (bb - nb - 1) * 256 + t;
    if (tid < 128 * 256) {
      int c = tid >> 8, k = tid & 255;
      float v = (k < 128) ? Wl2[k * 128 + c] : Wr2[(k - 128) * 128 + c];
      wt[tid] = f32_to_bf16(v);
    }
  }
}

// ---- bin pass 3: scatter packed (src<<6 | dst&63) at precomputed bases ------
__global__ __launch_bounds__(256) void k_bscatter(const int* __restrict__ ei,
                                                  const int* __restrict__ bbase,
                                                  const unsigned short* __restrict__ rel,
                                                  unsigned int* __restrict__ ebuf, int E, int nb) {
  __shared__ int h[NBMAX];                   // in-block rank cursors
  __shared__ int base[NBMAX];
  int t = threadIdx.x;
  const unsigned short* rr = rel + (size_t)blockIdx.x * nb;
  for (int i = t; i < nb; i += 256) {
    h[i] = 0;
    base[i] = bbase[i] + (int)rr[i];
  }
  __syncthreads();
  int tbeg = blockIdx.x * EDGE_TILE;
  int tend = min(tbeg + EDGE_TILE, E);
  const int* srcp = ei;
  const int* dstp = ei + E;
  for (int i = tbeg + t; i < tend; i += 256) {
    int d = dstp[i];
    int b = d >> 6;
    int r = atomicAdd(&h[b], 1);
    ebuf[base[b] + r] = ((unsigned)srcp[i] << 6) | (unsigned)(d & 63);
  }
}

// ---- bin pass 4: per-bucket (64 nodes) CSR + x-agg + layer-1 dense ----------
__global__ __launch_bounds__(256) void k_bucket_csr(const unsigned int* __restrict__ ebuf,
                                                    const int* __restrict__ bbase,
                                                    const float* __restrict__ x,
                                                    const float* __restrict__ Wl,
                                                    const float* __restrict__ Wr,
                                                    const float* __restrict__ b1,
                                                    int* __restrict__ offs, int* __restrict__ csr,
                                                    unsigned int* __restrict__ h16,
                                                    unsigned short* __restrict__ h8,
                                                    int N, int nb) {
  __shared__ int deg[64];
  __shared__ int loff[64];
  __shared__ int exo[64];
  __shared__ int cur[64];
  __shared__ float sx0[64];
  __shared__ float sx1[64];
  int b = blockIdx.x;
  int t = threadIdx.x;
  int lo = bbase[b], hi = bbase[b + 1];
  if (t < 64) deg[t] = 0;
  __syncthreads();

  // pass 1: degree histogram only (1 int atomic per edge)
  for (int i = lo + t; i < hi; i += 256) atomicAdd(&deg[ebuf[i] & 63], 1);
  __syncthreads();

  // scan degrees -> exclusive offsets
  if (t < 64) loff[t] = deg[t];
  __syncthreads();
  for (int st = 1; st < 64; st <<= 1) {
    int v = 0;
    if (t < 64 && t >= st) v = loff[t - st];
    __syncthreads();
    if (t < 64) loff[t] += v;
    __syncthreads();
  }
  if (t < 64) {
    int ex = loff[t] - deg[t];                 // exclusive prefix
    exo[t] = ex;
    cur[t] = ex;
    int node = b * 64 + t;
    if (node < N) offs[node] = lo + ex;
  }
  if (b == nb - 1 && t == 0) offs[N] = hi;
  __syncthreads();

  // pass 2: rank-scatter into csr (node-sorted within bucket)
  for (int i = lo + t; i < hi; i += 256) {
    unsigned int e = ebuf[i];
    int r = atomicAdd(&cur[e & 63], 1);
    csr[lo + r] = (int)(e >> 6);
  }
  __syncthreads();

  // pass 3: per-node x-sum over contiguous csr range (4 threads/node)
  const float2* x2 = (const float2*)x;
  {
    int nl = t >> 2;                          // 0..63
    int node = b * 64 + nl;
    float ax = 0.f, ay = 0.f;
    if (node < N) {
      int base = lo + exo[nl];
      int dg = deg[nl];
      for (int j = (t & 3); j < dg; j += 4) {
        float2 v = x2[csr[base + j]];
        ax += v.x;
        ay += v.y;
      }
    }
    ax += __shfl_xor(ax, 1);
    ay += __shfl_xor(ay, 1);
    ax += __shfl_xor(ax, 2);
    ay += __shfl_xor(ay, 2);
    if ((t & 3) == 0) { sx0[nl] = ax; sx1[nl] = ay; }
  }
  __syncthreads();

  // layer-1 dense: 64 nodes x 64 col-pairs, 16 iters/thread
  int nfirst = b * 64;
  for (int i = t; i < 64 * 64; i += 256) {
    int nl = i >> 6;
    int node = nfirst + nl;
    if (node >= N) break;                     // nl nondecreasing in i
    int c = (i & 63) * 2;
    int dg = deg[nl];
    float sc = 1.0f / (float)max(dg, 1);
    float a0 = sx0[nl] * sc, a1 = sx1[nl] * sc;
    float2 xv = x2[node];
    float r0 = fmaf(a0, Wl[c],     fmaf(a1, Wl[128 + c],     fmaf(xv.x, Wr[c],     fmaf(xv.y, Wr[128 + c],     b1[c]))));
    float r1 = fmaf(a0, Wl[c + 1], fmaf(a1, Wl[128 + c + 1], fmaf(xv.x, Wr[c + 1], fmaf(xv.y, Wr[128 + c + 1], b1[c + 1]))));
    r0 = r0 > 0.f ? r0 : 0.f;
    r1 = r1 > 0.f ? r1 : 0.f;
    unsigned int packed = (unsigned int)f32_to_bf16(r0) | ((unsigned int)f32_to_bf16(r1) << 16);
    h16[(size_t)node * 64 + (i & 63)] = packed;
    unsigned int p8 = (unsigned int)__builtin_amdgcn_cvt_pk_fp8_f32(r0, r1, 0, false);
    h8[(size_t)node * 64 + (i & 63)] = (unsigned short)(p8 & 0xffffu);
  }
}

// ---- layer-2 aggregation: 8 nodes/wave, 8 lanes/node, 16 cols/lane ----------
// R12: cross-iteration prefetch — rows (t,t+1) load while (t-2,t-1) ACC8.
#define ACC8(v)                                                                              \
  do {                                                                                       \
    f32x2 p;                                                                                 \
    p = __builtin_amdgcn_cvt_pk_f32_fp8((int)(v).x, false); acc[0] += p[0];  acc[1] += p[1]; \
    p = __builtin_amdgcn_cvt_pk_f32_fp8((int)(v).x, true);  acc[2] += p[0];  acc[3] += p[1]; \
    p = __builtin_amdgcn_cvt_pk_f32_fp8((int)(v).y, false); acc[4] += p[0];  acc[5] += p[1]; \
    p = __builtin_amdgcn_cvt_pk_f32_fp8((int)(v).y, true);  acc[6] += p[0];  acc[7] += p[1]; \
    p = __builtin_amdgcn_cvt_pk_f32_fp8((int)(v).z, false); acc[8] += p[0];  acc[9] += p[1]; \
    p = __builtin_amdgcn_cvt_pk_f32_fp8((int)(v).z, true);  acc[10] += p[0]; acc[11] += p[1];\
    p = __builtin_amdgcn_cvt_pk_f32_fp8((int)(v).w, false); acc[12] += p[0]; acc[13] += p[1];\
    p = __builtin_amdgcn_cvt_pk_f32_fp8((int)(v).w, true);  acc[14] += p[0]; acc[15] += p[1];\
  } while (0)

__global__ __launch_bounds__(256) void k_agg2(const int* __restrict__ offs, const int* __restrict__ csr,
                                              const unsigned char* __restrict__ h8,
                                              unsigned int* __restrict__ a16, int n) {
  int wv   = threadIdx.x >> 6;
  int lane = threadIdx.x & 63;
  int sub  = lane >> 3;          // node slot within wave: 0..7
  int cb   = lane & 7;           // 16-col block: cols cb*16 .. cb*16+15
  int node = blockIdx.x * 32 + wv * 8 + sub;
  if (node >= n) return;
  int beg = offs[node];
  int end = offs[node + 1];
  int deg = end - beg;
  const unsigned char* hb = h8 + cb * 16;

  float acc[16];
#pragma unroll
  for (int j = 0; j < 16; ++j) acc[j] = 0.f;

  int t = 0;
  if (deg >= 2) {
    int s0 = csr[beg];
    int s1 = csr[beg + 1];
    uint4 c0 = *(const uint4*)(hb + (size_t)s0 * 128);
    uint4 c1 = *(const uint4*)(hb + (size_t)s1 * 128);
    for (t = 2; t + 1 < deg; t += 2) {
      int n0 = csr[beg + t];
      int n1 = csr[beg + t + 1];
      uint4 p0 = *(const uint4*)(hb + (size_t)n0 * 128);   // prefetch next pair
      uint4 p1 = *(const uint4*)(hb + (size_t)n1 * 128);
      ACC8(c0);
      ACC8(c1);
      c0 = p0; c1 = p1;
    }
    ACC8(c0);
    ACC8(c1);
  }
  if (t < deg) {
    int s0 = csr[beg + t];
    uint4 v0 = *(const uint4*)(hb + (size_t)s0 * 128);
    ACC8(v0);
  }

  float scale = 1.0f / (float)max(deg, 1);
  unsigned int u[8];
#pragma unroll
  for (int k = 0; k < 8; ++k)
    u[k] = (unsigned int)f32_to_bf16(acc[2 * k] * scale) |
           ((unsigned int)f32_to_bf16(acc[2 * k + 1] * scale) << 16);
  unsigned int* dst = a16 + (size_t)node * 64 + cb * 8;   // row = 64 uints
  *(uint4*)dst       = make_uint4(u[0], u[1], u[2], u[3]);
  *(uint4*)(dst + 4) = make_uint4(u[4], u[5], u[6], u[7]);
}

// ---- layer-2 GEMM: out[N,128] = [agg2|h](bf16) @ Wt(bf16) + b2, MFMA --------
__global__ __launch_bounds__(256) void k_gemm(const unsigned short* __restrict__ a16,
                                              const unsigned short* __restrict__ h16,
                                              const unsigned short* __restrict__ wt,
                                              const float* __restrict__ b2,
                                              float* __restrict__ out, int nrows) {
  __shared__ unsigned short bs[64 * 264];   // 33792 B
  int half = blockIdx.x & 1;
  int tg   = blockIdx.x >> 1;

#pragma unroll
  for (int i = 0; i < 8; ++i) {
    int c = threadIdx.x + i * 256;          // 0..2047
    int row = c >> 5, off = c & 31;         // off in 16B units
    *(uint4*)(bs + row * 264 + off * 8) =
        *(const uint4*)(wt + ((size_t)(half * 64 + row)) * 256 + off * 8);
  }
  __syncthreads();

  int wv   = threadIdx.x >> 6;
  int lane = threadIdx.x & 63;
  int m16 = lane & 15, quad = lane >> 4;
  int tile = tg * 4 + wv;
  if (tile * 16 >= nrows) return;

  int r  = tile * 16 + m16;
  int rc = r < nrows ? r : nrows - 1;
  const unsigned short* arow = a16 + (size_t)rc * 128 + quad * 8;
  const unsigned short* hrow = h16 + (size_t)rc * 128 + quad * 8;

  s16x8 afrag[8];
#pragma unroll
  for (int c4 = 0; c4 < 4; ++c4) {
    afrag[c4]     = *(const s16x8*)(arow + c4 * 32);   // A[m][k], k-chunk c4
    afrag[4 + c4] = *(const s16x8*)(hrow + c4 * 32);
  }

  f32x4 acc[4];
#pragma unroll
  for (int t = 0; t < 4; ++t) acc[t] = (f32x4){0.f, 0.f, 0.f, 0.f};

  const unsigned short* bbase = bs + m16 * 264 + quad * 8;
#pragma unroll
  for (int ch = 0; ch < 8; ++ch) {
#pragma unroll
    for (int t = 0; t < 4; ++t) {
      s16x8 bf = *(const s16x8*)(bbase + t * 16 * 264 + ch * 32); // B[k][n]
      acc[t] = __builtin_amdgcn_mfma_f32_16x16x32_bf16(afrag[ch], bf, acc[t], 0, 0, 0);
    }
  }

#pragma unroll
  for (int t = 0; t < 4; ++t) {
    int col = half * 64 + t * 16 + m16;
    float bias = b2[col];
#pragma unroll
    for (int i = 0; i < 4; ++i) {
      int row = tile * 16 + quad * 4 + i;   // C/D: col=lane&15, row=quad*4+reg
      if (row < nrows) out[(size_t)row * 128 + col] = acc[t][i] + bias;
    }
  }
}

// ---------------------------------------------------------------------------
extern "C" void kernel_launch(void* const* d_in, const int* in_sizes, int n_in,
                              void* d_out, int out_size, void* d_ws, size_t ws_size,
                              hipStream_t stream) {
  const float* x    = (const float*)d_in[0];
  const int*   ei   = (const int*)d_in[1];
  const float* Wl1  = (const float*)d_in[2];
  const float* Wr1  = (const float*)d_in[3];
  const float* b1   = (const float*)d_in[4];
  const float* Wl2  = (const float*)d_in[5];
  const float* Wr2  = (const float*)d_in[6];
  const float* b2   = (const float*)d_in[7];
  float* out = (float*)d_out;

  const int N = in_sizes[0] / 2;     // 100000
  const int E = in_sizes[1] / 2;     // 1600000
  const int nb = (N + 63) >> 6;      // 1563 buckets (64 nodes each)
  const int nblk_e = (E + EDGE_TILE - 1) / EDGE_TILE;   // 391

  // workspace carve-up (256B aligned)
  char* p = (char*)d_ws;
  auto take = [&](size_t bytes) { char* r = p; p += (bytes + 255) & ~(size_t)255; return r; };
  int* bcnt            = (int*)take((size_t)NBMAX * 4);
  int* bbase           = (int*)take((size_t)(NBMAX + 1) * 4);
  unsigned short* hcnt = (unsigned short*)take((size_t)nblk_e * nb * 2);
  unsigned short* rel  = (unsigned short*)take((size_t)nblk_e * nb * 2);
  int* offs            = (int*)take((size_t)(N + 1) * 4);
  int* csr             = (int*)take((size_t)E * 4);
  unsigned int* ebuf   = (unsigned int*)take((size_t)E * 4);
  unsigned short* h16  = (unsigned short*)take((size_t)N * 128 * 2);
  unsigned short* a16  = (unsigned short*)take((size_t)N * 128 * 2);
  unsigned short* h8   = (unsigned short*)take((size_t)N * 128);
  unsigned short* wt   = (unsigned short*)take((size_t)128 * 256 * 2);

  const int ntiles = (N + 15) / 16;                      // 6250

  hipMemsetAsync(bcnt, 0, (size_t)NBMAX * 4, stream);

  k_bhist     <<<nblk_e, 256, 0, stream>>>(ei, bcnt, hcnt, E, nb);
  k_scans     <<<nb + 1 + 128, 256, 0, stream>>>(hcnt, rel, bcnt, bbase, Wl2, Wr2, wt,
                                                 nblk_e, nb, E);
  k_bscatter  <<<nblk_e, 256, 0, stream>>>(ei, bbase, rel, ebuf, E, nb);
  k_bucket_csr<<<nb, 256, 0, stream>>>(ebuf, bbase, x, Wl1, Wr1, b1, offs, csr,
                                       (unsigned int*)h16, h8, N, nb);
  k_agg2      <<<(N + 31) / 32, 256, 0, stream>>>(offs, csr, (const unsigned char*)h8,
                                                  (unsigned int*)a16, N);
  k_gemm      <<<((ntiles + 3) / 4) * 2, 256, 0, stream>>>(a16, h16, wt, b2, out, N);
}